// Round 1
// baseline (313.454 us; speedup 1.0000x reference)
//
#include <hip/hip_runtime.h>
#include <hip/hip_bf16.h>
#include <math.h>

// Problem dims
#define B_DIM 32
#define S_DIM 256
#define F_DIM 64
#define U_DIM 128
#define TOK   (B_DIM * S_DIM)   // 8192 tokens
#define KDIM  (F_DIM * U_DIM)   // 8192 reduction dim
#define N3    (3 * U_DIM)       // 384 fused output cols (elu|gate|proj)

// GEMM tiling
#define BM   32
#define BK   64
#define ASTR 72                 // a_lds row stride in bf16 elems (16B-aligned, 2-way banks)

typedef __bf16 bf16x8 __attribute__((ext_vector_type(8)));
typedef float  f32x4  __attribute__((ext_vector_type(4)));

// ---------------------------------------------------------------------------
// Kernel 1: pack the three [K=8192][U=128] f32 weight matrices into
// Bpack[n][k] bf16 (n in [0,384)), k-contiguous for MFMA B-fragment loads.
// grid = 3 * (KDIM/32) blocks, 256 threads.
// ---------------------------------------------------------------------------
__global__ __launch_bounds__(256) void vsn_prep(
    const float* __restrict__ elu_w,
    const float* __restrict__ gate_w,
    const float* __restrict__ proj_w,
    __bf16* __restrict__ Bp)
{
    __shared__ float tile[32][U_DIM + 1];
    const int mat = blockIdx.x / (KDIM / 32);
    const int kb  = blockIdx.x % (KDIM / 32);
    const float* W = (mat == 0) ? elu_w : (mat == 1 ? gate_w : proj_w);
    const int t = threadIdx.x;

    // load 32 k-rows x 128 n cols, coalesced
#pragma unroll
    for (int i = 0; i < 16; ++i) {
        int idx = i * 256 + t;
        int r = idx >> 7;        // k row 0..31
        int c = idx & 127;       // n col
        tile[r][c] = W[(size_t)(kb * 32 + r) * U_DIM + c];
    }
    __syncthreads();
    // write transposed: Bpack[(mat*128 + c) * K + kb*32 + r]
#pragma unroll
    for (int i = 0; i < 16; ++i) {
        int idx = i * 256 + t;
        int c = idx >> 5;        // n col 0..127
        int r = idx & 31;        // k row 0..31
        Bp[(size_t)(mat * U_DIM + c) * KDIM + kb * 32 + r] = (__bf16)tile[r][c];
    }
}

// ---------------------------------------------------------------------------
// Kernel 2: fused feat(gelu) + 3-way GEMM.
// Grid = TOK/BM = 256 WGs x 256 threads (4 waves).
// Wave w computes cols [w*96, w*96+96) for all 32 tokens of the block.
// H[tok][384] f32 = raw sums (elu | gate | proj), biases added in epilogue.
// ---------------------------------------------------------------------------
__global__ __launch_bounds__(256) void vsn_gemm(
    const float* __restrict__ x,
    const float* __restrict__ fw,
    const float* __restrict__ fb,
    const __bf16* __restrict__ Bp,
    float* __restrict__ H)
{
    __shared__ float  x_lds[BM][F_DIM + 1];   // 32x65 f32
    __shared__ __bf16 fw_lds[KDIM];           // 16KB
    __shared__ __bf16 fb_lds[KDIM];           // 16KB
    __shared__ __bf16 a_lds[BM][ASTR];        // 32x72 bf16

    const int t    = threadIdx.x;
    const int wave = t >> 6;
    const int lane = t & 63;
    const int tok0 = blockIdx.x * BM;
    const int nbase = wave * 96;

    // stage x tile (32 tok x 64 f)
#pragma unroll
    for (int i = 0; i < 8; ++i) {
        int idx = i * 256 + t;
        x_lds[idx >> 6][idx & 63] = x[(size_t)tok0 * F_DIM + idx];
    }
    // stage fw/fb as bf16 (k-flat = f*128+u, matches concat index)
#pragma unroll
    for (int i = 0; i < 32; ++i) {
        int k = i * 256 + t;
        fw_lds[k] = (__bf16)fw[k];
        fb_lds[k] = (__bf16)fb[k];
    }

    f32x4 acc[2][6];
#pragma unroll
    for (int i = 0; i < 2; ++i)
#pragma unroll
        for (int j = 0; j < 6; ++j)
            acc[i][j] = (f32x4){0.f, 0.f, 0.f, 0.f};

    const int m_a  = t >> 3;        // 0..31 : A-tile row this thread computes
    const int kk8  = (t & 7) * 8;   // 0..56 : A-tile k-subcolumn (8 elems)

    __syncthreads();

    for (int kb = 0; kb < KDIM / BK; ++kb) {
        const int k0 = kb * BK;

        // ---- cooperative A-tile: feat = gelu(x*fw + fb), bf16, once per WG
        {
            const float xs = x_lds[m_a][(k0 + kk8) >> 7];
            bf16x8 wv = *(const bf16x8*)&fw_lds[k0 + kk8];
            bf16x8 bv = *(const bf16x8*)&fb_lds[k0 + kk8];
            bf16x8 av;
#pragma unroll
            for (int j = 0; j < 8; ++j) {
                float z = fmaf(xs, (float)wv[j], (float)bv[j]);
                float g = 0.5f * z * (1.0f + erff(z * 0.70710678f));
                av[j] = (__bf16)g;
            }
            *(bf16x8*)&a_lds[m_a][kk8] = av;
        }

        // ---- B fragments straight from global (L2/LLC-hot)
        bf16x8 bfrag[2][6];
#pragma unroll
        for (int ks = 0; ks < 2; ++ks)
#pragma unroll
            for (int j = 0; j < 6; ++j) {
                int n = nbase + j * 16 + (lane & 15);
                int k = k0 + ks * 32 + (lane >> 4) * 8;
                bfrag[ks][j] = *(const bf16x8*)&Bp[(size_t)n * KDIM + k];
            }

        __syncthreads();   // a_lds ready

        // ---- MFMA
#pragma unroll
        for (int ks = 0; ks < 2; ++ks) {
            bf16x8 afrag[2];
#pragma unroll
            for (int i = 0; i < 2; ++i)
                afrag[i] = *(const bf16x8*)&a_lds[i * 16 + (lane & 15)][ks * 32 + (lane >> 4) * 8];
#pragma unroll
            for (int i = 0; i < 2; ++i)
#pragma unroll
                for (int j = 0; j < 6; ++j)
                    acc[i][j] = __builtin_amdgcn_mfma_f32_16x16x32_bf16(
                        afrag[i], bfrag[ks][j], acc[i][j], 0, 0, 0);
        }

        __syncthreads();   // a_lds consumed, safe to overwrite next iter
    }

    // ---- write raw sums: C/D layout col=lane&15, row=(lane>>4)*4+r (m89)
#pragma unroll
    for (int i = 0; i < 2; ++i)
#pragma unroll
        for (int j = 0; j < 6; ++j)
#pragma unroll
            for (int r = 0; r < 4; ++r) {
                int row = tok0 + i * 16 + (lane >> 4) * 4 + r;
                int col = nbase + j * 16 + (lane & 15);
                H[(size_t)row * N3 + col] = acc[i][j][r];
            }
}

// ---------------------------------------------------------------------------
// Kernel 3: epilogue, one wave per token.
// h1 = elu(H[:,0:128]+elu_b); gate = sigmoid(H[:,128:256]+gate_b);
// h = gate*(h1@lin_w+lin_b) + H[:,256:384]; LN; softmax(y@sm_w+sm_b);
// out0 = x*w, out1 = w.
// ---------------------------------------------------------------------------
__global__ __launch_bounds__(256) void vsn_epi(
    const float* __restrict__ x,
    const float* __restrict__ H,
    const float* __restrict__ elu_b,
    const float* __restrict__ lin_w,
    const float* __restrict__ lin_b,
    const float* __restrict__ gate_b,
    const float* __restrict__ ln_g,
    const float* __restrict__ ln_b,
    const float* __restrict__ sm_w,
    const float* __restrict__ sm_b,
    float* __restrict__ out)
{
    __shared__ float sh[4][U_DIM];
    const int wave = threadIdx.x >> 6;
    const int lane = threadIdx.x & 63;
    const int tok  = blockIdx.x * 4 + wave;
    const float* Ht = H + (size_t)tok * N3;

    float a0 = Ht[lane],        a1 = Ht[64 + lane];
    float g0 = Ht[128 + lane],  g1 = Ht[192 + lane];
    float p0 = Ht[256 + lane],  p1 = Ht[320 + lane];

    float e0 = a0 + elu_b[lane], e1 = a1 + elu_b[64 + lane];
    float h1_0 = (e0 > 0.f) ? e0 : expm1f(e0);
    float h1_1 = (e1 > 0.f) ? e1 : expm1f(e1);

    float gg0 = g0 + gate_b[lane], gg1 = g1 + gate_b[64 + lane];
    float gate0 = 1.0f / (1.0f + __expf(-gg0));
    float gate1 = 1.0f / (1.0f + __expf(-gg1));

    sh[wave][lane] = h1_0;
    sh[wave][64 + lane] = h1_1;
    __syncthreads();

    float h2_0 = lin_b[lane], h2_1 = lin_b[64 + lane];
    for (int v = 0; v < U_DIM; ++v) {
        float h1v = sh[wave][v];
        h2_0 = fmaf(h1v, lin_w[v * U_DIM + lane],      h2_0);
        h2_1 = fmaf(h1v, lin_w[v * U_DIM + 64 + lane], h2_1);
    }
    float h0 = gate0 * h2_0 + p0;
    float h1 = gate1 * h2_1 + p1;

    // LayerNorm over 128 (2 elems per lane, wave reduce)
    float s = h0 + h1;
#pragma unroll
    for (int off = 32; off; off >>= 1) s += __shfl_xor(s, off);
    float mu = s * (1.0f / 128.0f);
    float d0 = h0 - mu, d1 = h1 - mu;
    float vq = d0 * d0 + d1 * d1;
#pragma unroll
    for (int off = 32; off; off >>= 1) vq += __shfl_xor(vq, off);
    float rstd = rsqrtf(vq * (1.0f / 128.0f) + 1e-3f);
    float y0 = d0 * rstd * ln_g[lane]      + ln_b[lane];
    float y1 = d1 * rstd * ln_g[64 + lane] + ln_b[64 + lane];

    __syncthreads();
    sh[wave][lane] = y0;
    sh[wave][64 + lane] = y1;
    __syncthreads();

    // logits over F=64, lane = feature id
    float lg = sm_b[lane];
    for (int u = 0; u < U_DIM; ++u)
        lg = fmaf(sh[wave][u], sm_w[u * F_DIM + lane], lg);

    // softmax across 64 lanes
    float mx = lg;
#pragma unroll
    for (int off = 32; off; off >>= 1) mx = fmaxf(mx, __shfl_xor(mx, off));
    float ex = __expf(lg - mx);
    float se = ex;
#pragma unroll
    for (int off = 32; off; off >>= 1) se += __shfl_xor(se, off);
    float wgt = ex / se;

    float xv = x[(size_t)tok * F_DIM + lane];
    out[(size_t)tok * F_DIM + lane] = xv * wgt;
    out[(size_t)TOK * F_DIM + (size_t)tok * F_DIM + lane] = wgt;
}

// ---------------------------------------------------------------------------
extern "C" void kernel_launch(void* const* d_in, const int* in_sizes, int n_in,
                              void* d_out, int out_size, void* d_ws, size_t ws_size,
                              hipStream_t stream)
{
    const float* x      = (const float*)d_in[0];
    const float* fw     = (const float*)d_in[1];
    const float* fb     = (const float*)d_in[2];
    const float* elu_w  = (const float*)d_in[3];
    const float* elu_b  = (const float*)d_in[4];
    const float* lin_w  = (const float*)d_in[5];
    const float* lin_b  = (const float*)d_in[6];
    const float* gate_w = (const float*)d_in[7];
    const float* gate_b = (const float*)d_in[8];
    const float* proj_w = (const float*)d_in[9];
    const float* ln_g   = (const float*)d_in[10];
    const float* ln_b   = (const float*)d_in[11];
    const float* sm_w   = (const float*)d_in[12];
    const float* sm_b   = (const float*)d_in[13];

    __bf16* Bpack = (__bf16*)d_ws;                                   // 384*8192*2 = 6291456 B
    float*  H     = (float*)((char*)d_ws + (size_t)N3 * KDIM * 2);   // 8192*384*4 = 12582912 B

    vsn_prep<<<3 * (KDIM / 32), 256, 0, stream>>>(elu_w, gate_w, proj_w, Bpack);
    vsn_gemm<<<TOK / BM, 256, 0, stream>>>(x, fw, fb, Bpack, H);
    vsn_epi<<<TOK / 4, 256, 0, stream>>>(x, H, elu_b, lin_w, lin_b, gate_b,
                                         ln_g, ln_b, sm_w, sm_b, (float*)d_out);
}

// Round 2
// 113.110 us; speedup vs baseline: 2.7712x; 2.7712x over previous
//
#include <hip/hip_runtime.h>
#include <hip/hip_bf16.h>
#include <math.h>

// Problem dims
#define B_DIM 32
#define S_DIM 256
#define F_DIM 64
#define U_DIM 128
#define TOK   (B_DIM * S_DIM)   // 8192 tokens
#define KDIM  (F_DIM * U_DIM)   // 8192 reduction dim
#define N3    (3 * U_DIM)       // 384 fused output cols (elu|gate|proj)

// GEMM tiling
#define BM2  64
#define BK   64
#define ASTR 72                 // a_lds row stride (bf16 elems)

typedef __bf16 bf16x8 __attribute__((ext_vector_type(8)));
typedef float  f32x4  __attribute__((ext_vector_type(4)));

// tanh-approx GELU: 0.5*z*(1+tanh(0.79788456*(z+0.044715 z^3)))
//  = z * e/(e+1), e = exp(1.59576912*(z+0.044715 z^3)).  |err vs erf-gelu| < ~1e-3.
__device__ __forceinline__ float gelu_fast(float z) {
    float u2 = 1.5957691216057308f * fmaf(0.044715f * z, z * z, z);
    float e  = __expf(u2);
    float r  = __builtin_amdgcn_rcpf(e + 1.0f);  // inf -> 0, ok
    return z - z * r;
}

// ---------------------------------------------------------------------------
// Kernel 1: pack W[k][n] f32 (3 mats) -> Bp[k/32][n(384)][k%32] bf16.
// B-fragment loads in the GEMM then cover 1KB contiguous per wave inst.
// grid = 3 * (KDIM/32), 256 threads.
// ---------------------------------------------------------------------------
__global__ __launch_bounds__(256) void vsn_prep2(
    const float* __restrict__ elu_w,
    const float* __restrict__ gate_w,
    const float* __restrict__ proj_w,
    __bf16* __restrict__ Bp)
{
    __shared__ float tile[32][U_DIM + 1];
    const int mat = blockIdx.x / (KDIM / 32);
    const int kb  = blockIdx.x % (KDIM / 32);
    const float* W = (mat == 0) ? elu_w : (mat == 1 ? gate_w : proj_w);
    const int t = threadIdx.x;

#pragma unroll
    for (int i = 0; i < 16; ++i) {
        int idx = i * 256 + t;
        int r = idx >> 7;        // k row 0..31
        int c = idx & 127;       // n col
        tile[r][c] = W[(size_t)(kb * 32 + r) * U_DIM + c];
    }
    __syncthreads();
#pragma unroll
    for (int i = 0; i < 16; ++i) {
        int idx = i * 256 + t;
        int c = idx >> 5;        // n col 0..127
        int r = idx & 31;        // k%32
        Bp[((size_t)kb * N3 + mat * U_DIM + c) * 32 + r] = (__bf16)tile[r][c];
    }
}

// ---------------------------------------------------------------------------
// Kernel 2: fused gelu-feat + 3-way GEMM, split-K.
// grid = (TOK/BM2, KSPLIT), 256 threads (4 waves, wave = 96 n-cols).
// Writes f32 partial sums Hp[s][tok][384].
// ---------------------------------------------------------------------------
template<int KSPLIT>
__global__ __launch_bounds__(256, 2) void vsn_gemm2(
    const float* __restrict__ x,
    const float* __restrict__ fw,
    const float* __restrict__ fb,
    const __bf16* __restrict__ Bp,
    float* __restrict__ Hp)
{
    constexpr int KRANGE = KDIM / KSPLIT;
    constexpr int NST    = KRANGE / BK;
    constexpr int NF     = KRANGE / U_DIM;          // x features this split
    constexpr int NBUF   = (KSPLIT == 1) ? 1 : 2;   // keep LDS <= 64K for KSPLIT=1

    __shared__ float  x_lds[BM2][NF + 1];
    __shared__ __bf16 fw_lds[KRANGE];
    __shared__ __bf16 fb_lds[KRANGE];
    __shared__ __bf16 a_lds[NBUF][BM2][ASTR];

    const int t    = threadIdx.x;
    const int wave = t >> 6;
    const int lane = t & 63;
    const int tok0  = blockIdx.x * BM2;
    const int s     = blockIdx.y;
    const int kbase = s * KRANGE;
    const int nbase = wave * 96;
    const int lr = lane & 15;
    const int lk = (lane >> 4) * 8;

    // ---- stage x slice (BM2 x NF f32)
#pragma unroll
    for (int i = 0; i < (BM2 * NF) / 256; ++i) {
        int idx = i * 256 + t;
        int r = idx / NF, c = idx % NF;
        x_lds[r][c] = x[(size_t)(tok0 + r) * F_DIM + (kbase >> 7) + c];
    }
    // ---- stage fw/fb slice as bf16
#pragma unroll
    for (int i = 0; i < KRANGE / 256; ++i) {
        int k = i * 256 + t;
        fw_lds[k] = (__bf16)fw[kbase + k];
        fb_lds[k] = (__bf16)fb[kbase + k];
    }

    f32x4 acc[4][6];
#pragma unroll
    for (int i = 0; i < 4; ++i)
#pragma unroll
        for (int j = 0; j < 6; ++j)
            acc[i][j] = (f32x4){0.f, 0.f, 0.f, 0.f};

    const int m_a = t >> 2;          // A-tile row this thread computes
    const int kk  = (t & 3) * 16;    // A-tile k-subcol (16 elems)

    auto gelu_write = [&](int st2, int buf) {
        const int k0 = st2 * BK;
        const float xs = x_lds[m_a][(k0 + kk) >> 7];
#pragma unroll
        for (int h = 0; h < 2; ++h) {
            bf16x8 wv = *(const bf16x8*)&fw_lds[k0 + kk + h * 8];
            bf16x8 bv = *(const bf16x8*)&fb_lds[k0 + kk + h * 8];
            bf16x8 av;
#pragma unroll
            for (int j = 0; j < 8; ++j) {
                float z = fmaf(xs, (float)wv[j], (float)bv[j]);
                av[j] = (__bf16)gelu_fast(z);
            }
            *(bf16x8*)&a_lds[buf][m_a][kk + h * 8] = av;
        }
    };

    const __bf16* bbase = Bp + (size_t)(kbase >> 5) * (N3 * 32)
                             + (size_t)(nbase + lr) * 32 + lk;

    __syncthreads();                  // staging visible
    if (NBUF == 2) gelu_write(0, 0);

    for (int st = 0; st < NST; ++st) {
        const int cur = (NBUF == 2) ? (st & 1) : 0;
        if (NBUF == 1) {
            gelu_write(st, 0);
            __syncthreads();
        } else {
            __syncthreads();          // a_lds[cur] ready; prev reads of cur^1 done
        }

        // B fragments: fully coalesced 1KB wave loads from packed layout
        bf16x8 bfrag[2][6];
#pragma unroll
        for (int ksi = 0; ksi < 2; ++ksi)
#pragma unroll
            for (int j = 0; j < 6; ++j)
                bfrag[ksi][j] = *(const bf16x8*)(bbase
                    + (size_t)(st * 2 + ksi) * (N3 * 32) + j * 512);

        // A fragments from LDS
        bf16x8 afrag[2][4];
#pragma unroll
        for (int ksi = 0; ksi < 2; ++ksi)
#pragma unroll
            for (int i = 0; i < 4; ++i)
                afrag[ksi][i] = *(const bf16x8*)&a_lds[cur][i * 16 + lr][ksi * 32 + lk];

        // overlap next A-tile gelu with this step's MFMAs
        if (NBUF == 2 && st + 1 < NST) gelu_write(st + 1, cur ^ 1);

#pragma unroll
        for (int ksi = 0; ksi < 2; ++ksi)
#pragma unroll
            for (int i = 0; i < 4; ++i)
#pragma unroll
                for (int j = 0; j < 6; ++j)
                    acc[i][j] = __builtin_amdgcn_mfma_f32_16x16x32_bf16(
                        afrag[ksi][i], bfrag[ksi][j], acc[i][j], 0, 0, 0);

        if (NBUF == 1) __syncthreads();
    }

    // ---- write f32 partials (C/D layout: col=lane&15, row=(lane>>4)*4+r)
    float* Hs = Hp + (size_t)s * ((size_t)TOK * N3);
    const int r0 = (lane >> 4) * 4;
#pragma unroll
    for (int i = 0; i < 4; ++i)
#pragma unroll
        for (int j = 0; j < 6; ++j)
#pragma unroll
            for (int r = 0; r < 4; ++r)
                Hs[(size_t)(tok0 + i * 16 + r0 + r) * N3 + nbase + j * 16 + lr]
                    = acc[i][j][r];
}

// ---------------------------------------------------------------------------
// Kernel 3: epilogue, one wave per token; sums KSPLIT partials.
// ---------------------------------------------------------------------------
template<int KSPLIT>
__global__ __launch_bounds__(256) void vsn_epi2(
    const float* __restrict__ x,
    const float* __restrict__ Hp,
    const float* __restrict__ elu_b,
    const float* __restrict__ lin_w,
    const float* __restrict__ lin_b,
    const float* __restrict__ gate_b,
    const float* __restrict__ ln_g,
    const float* __restrict__ ln_b,
    const float* __restrict__ sm_w,
    const float* __restrict__ sm_b,
    float* __restrict__ out)
{
    __shared__ float sh[4][U_DIM];
    const int wave = threadIdx.x >> 6;
    const int lane = threadIdx.x & 63;
    const int tok  = blockIdx.x * 4 + wave;

    float a0 = 0.f, a1 = 0.f, g0 = 0.f, g1 = 0.f, p0 = 0.f, p1 = 0.f;
#pragma unroll
    for (int s2 = 0; s2 < KSPLIT; ++s2) {
        const float* Ht = Hp + (size_t)s2 * ((size_t)TOK * N3) + (size_t)tok * N3;
        a0 += Ht[lane];        a1 += Ht[64 + lane];
        g0 += Ht[128 + lane];  g1 += Ht[192 + lane];
        p0 += Ht[256 + lane];  p1 += Ht[320 + lane];
    }

    float e0 = a0 + elu_b[lane], e1 = a1 + elu_b[64 + lane];
    float h1_0 = (e0 > 0.f) ? e0 : expm1f(e0);
    float h1_1 = (e1 > 0.f) ? e1 : expm1f(e1);

    float gg0 = g0 + gate_b[lane], gg1 = g1 + gate_b[64 + lane];
    float gate0 = 1.0f / (1.0f + __expf(-gg0));
    float gate1 = 1.0f / (1.0f + __expf(-gg1));

    sh[wave][lane] = h1_0;
    sh[wave][64 + lane] = h1_1;
    __syncthreads();

    float h2_0 = lin_b[lane], h2_1 = lin_b[64 + lane];
    for (int v = 0; v < U_DIM; ++v) {
        float h1v = sh[wave][v];
        h2_0 = fmaf(h1v, lin_w[v * U_DIM + lane],      h2_0);
        h2_1 = fmaf(h1v, lin_w[v * U_DIM + 64 + lane], h2_1);
    }
    float h0 = gate0 * h2_0 + p0;
    float h1 = gate1 * h2_1 + p1;

    // LayerNorm over 128
    float sum = h0 + h1;
#pragma unroll
    for (int off = 32; off; off >>= 1) sum += __shfl_xor(sum, off);
    float mu = sum * (1.0f / 128.0f);
    float d0 = h0 - mu, d1 = h1 - mu;
    float vq = d0 * d0 + d1 * d1;
#pragma unroll
    for (int off = 32; off; off >>= 1) vq += __shfl_xor(vq, off);
    float rstd = rsqrtf(vq * (1.0f / 128.0f) + 1e-3f);
    float y0 = d0 * rstd * ln_g[lane]      + ln_b[lane];
    float y1 = d1 * rstd * ln_g[64 + lane] + ln_b[64 + lane];

    __syncthreads();
    sh[wave][lane] = y0;
    sh[wave][64 + lane] = y1;
    __syncthreads();

    float lg = sm_b[lane];
    for (int u = 0; u < U_DIM; ++u)
        lg = fmaf(sh[wave][u], sm_w[u * F_DIM + lane], lg);

    float mx = lg;
#pragma unroll
    for (int off = 32; off; off >>= 1) mx = fmaxf(mx, __shfl_xor(mx, off));
    float ex = __expf(lg - mx);
    float se = ex;
#pragma unroll
    for (int off = 32; off; off >>= 1) se += __shfl_xor(se, off);
    float wgt = ex / se;

    float xv = x[(size_t)tok * F_DIM + lane];
    out[(size_t)tok * F_DIM + lane] = xv * wgt;
    out[(size_t)TOK * F_DIM + (size_t)tok * F_DIM + lane] = wgt;
}

// ---------------------------------------------------------------------------
extern "C" void kernel_launch(void* const* d_in, const int* in_sizes, int n_in,
                              void* d_out, int out_size, void* d_ws, size_t ws_size,
                              hipStream_t stream)
{
    const float* x      = (const float*)d_in[0];
    const float* fw     = (const float*)d_in[1];
    const float* fb     = (const float*)d_in[2];
    const float* elu_w  = (const float*)d_in[3];
    const float* elu_b  = (const float*)d_in[4];
    const float* lin_w  = (const float*)d_in[5];
    const float* lin_b  = (const float*)d_in[6];
    const float* gate_w = (const float*)d_in[7];
    const float* gate_b = (const float*)d_in[8];
    const float* proj_w = (const float*)d_in[9];
    const float* ln_g   = (const float*)d_in[10];
    const float* ln_b   = (const float*)d_in[11];
    const float* sm_w   = (const float*)d_in[12];
    const float* sm_b   = (const float*)d_in[13];

    const size_t bp_bytes = (size_t)N3 * KDIM * sizeof(__bf16);   // 6.3 MB
    const size_t h_bytes  = (size_t)TOK * N3 * sizeof(float);     // 12.6 MB
    __bf16* Bp = (__bf16*)d_ws;
    float*  Hp = (float*)((char*)d_ws + bp_bytes);

    // deterministic per-harness: ws_size is fixed
    const int ksplit = (ws_size >= bp_bytes + 4 * h_bytes) ? 4
                     : (ws_size >= bp_bytes + 2 * h_bytes) ? 2 : 1;

    vsn_prep2<<<3 * (KDIM / 32), 256, 0, stream>>>(elu_w, gate_w, proj_w, Bp);

    if (ksplit == 4) {
        vsn_gemm2<4><<<dim3(TOK / BM2, 4), 256, 0, stream>>>(x, fw, fb, Bp, Hp);
        vsn_epi2<4><<<TOK / 4, 256, 0, stream>>>(x, Hp, elu_b, lin_w, lin_b, gate_b,
                                                 ln_g, ln_b, sm_w, sm_b, (float*)d_out);
    } else if (ksplit == 2) {
        vsn_gemm2<2><<<dim3(TOK / BM2, 2), 256, 0, stream>>>(x, fw, fb, Bp, Hp);
        vsn_epi2<2><<<TOK / 4, 256, 0, stream>>>(x, Hp, elu_b, lin_w, lin_b, gate_b,
                                                 ln_g, ln_b, sm_w, sm_b, (float*)d_out);
    } else {
        vsn_gemm2<1><<<dim3(TOK / BM2, 1), 256, 0, stream>>>(x, fw, fb, Bp, Hp);
        vsn_epi2<1><<<TOK / 4, 256, 0, stream>>>(x, Hp, elu_b, lin_w, lin_b, gate_b,
                                                 ln_g, ln_b, sm_w, sm_b, (float*)d_out);
    }
}